// Round 14
// baseline (650.172 us; speedup 1.0000x reference)
//
#include <hip/hip_runtime.h>
#include <hip/hip_bf16.h>

#define DEV __device__ __forceinline__

typedef __attribute__((ext_vector_type(8))) short short8_t;
typedef __attribute__((ext_vector_type(4))) float f32x4;

DEV float gelu_erf(float x) { return 0.5f * x * (1.0f + erff(x * 0.70710678118654752440f)); }
DEV ushort f2bf(float v) { __hip_bfloat16 h = __float2bfloat16(v); return *(ushort*)&h; }

// XCD-aware bijective swizzle (grid must be a multiple of 8)
DEV int xcd_swz(int bid, int nwg) {
    int q = nwg >> 3;
    return (bid & 7) * q + (bid >> 3);
}

// ---------- weight prep: coalesced-read LDS-transpose ----------
// w4p [256][(kh*15+kw)*128+ic]; wp3' [128][75*64] k=tap*64+ic; wp2' [64][75*32] k=tap*32+ic
__global__ __launch_bounds__(256) void prep_k(
    const float* __restrict__ gw1, const float* __restrict__ gw2,
    const float* __restrict__ gw3, const float* __restrict__ gw4,
    const float* __restrict__ cw1,
    ushort* __restrict__ wp1, ushort* __restrict__ wp2,
    ushort* __restrict__ wp3, ushort* __restrict__ w4p,
    ushort* __restrict__ wp5, ushort* __restrict__ zp)
{
    __shared__ float lds[9600];
    const int tid = threadIdx.x;
    int blk = blockIdx.x;
    if (blk < 256) {                 // gw4 slice [128 ic][75 kc]
        const float* src = gw4 + (size_t)blk * 9600;
        for (int i = tid; i < 9600; i += 256) lds[i] = src[i];
        __syncthreads();
        ushort* dst = w4p + (size_t)blk * 9600;
        for (int p = tid; p < 9600; p += 256) {
            int ic = p & 127, kc = p >> 7;
            dst[p] = f2bf(lds[ic * 75 + kc]);
        }
        return;
    }
    blk -= 256;
    if (blk < 128) {                 // gw3 slice [64 ic][75 kc] -> wp3'[oc][tap*64+ic]
        const float* src = gw3 + (size_t)blk * 4800;
        for (int i = tid; i < 4800; i += 256) lds[i] = src[i];
        __syncthreads();
        ushort* dst = wp3 + (size_t)blk * 4800;
        for (int p = tid; p < 4800; p += 256) {
            int ic = p & 63, tap = p >> 6;
            dst[p] = f2bf(lds[ic * 75 + tap]);
        }
        return;
    }
    blk -= 128;
    if (blk < 64) {                  // gw2 slice [32 ic][75 kc] -> wp2'[oc][tap*32+ic]
        const float* src = gw2 + (size_t)blk * 2400;
        for (int i = tid; i < 2400; i += 256) lds[i] = src[i];
        __syncthreads();
        ushort* dst = wp2 + (size_t)blk * 2400;
        for (int p = tid; p < 2400; p += 256) {
            int ic = p & 31, tap = p >> 5;
            dst[p] = f2bf(lds[ic * 75 + tap]);
        }
        return;
    }
    // small tail: wp1 [32][96], wp5 [64][128], zp [256]
    for (int idx = tid; idx < 3072; idx += 256) {
        int oc = idx / 96, k = idx % 96;
        int kh = k >> 4, kw = k & 15;
        float v = (kh < 5 && kw < 15) ? gw1[oc * 75 + kh * 15 + kw] : 0.f;
        wp1[idx] = f2bf(v);
    }
    for (int idx = tid; idx < 8192; idx += 256) {
        int oc = idx >> 7, k = idx & 127;
        int kh = k >> 4, t = k & 15;
        int a = t >> 1, c = t & 1, kw = 2 * a + c - 1;
        float v = (kh < 7 && kw >= 0 && kw < 14) ? cw1[oc * 98 + kh * 14 + kw] : 0.f;
        wp5[idx] = f2bf(v);
    }
    for (int idx = tid; idx < 256; idx += 256) zp[idx] = 0;
}

// ---------- IC=1 implicit-GEMM MFMA conv (conv1, conv5) ----------
template <int M_BLK, int NOC, int NCH, int NWM, int NWN, int ST, bool F32IN, bool BNG>
__global__ __launch_bounds__(64 * NWM * NWN) void convmm1_k(
    const void* __restrict__ in_, const ushort* __restrict__ wp,
    const float* __restrict__ gamma, const float* __restrict__ beta,
    void* __restrict__ out_,
    int IH, int IWE, int OH, int OW, int NOWT, int PH)
{
    constexpr int NT = 64 * NWM * NWN;
    constexpr int NR = 2 * NCH;
    constexpr int SPAN = (M_BLK - 1) * ST + 16;
    constexpr int SSTR = ((SPAN + 16 + 7) & ~7) + 8;
    constexpr int STAGE_B = NR * SSTR * 2;
    constexpr int TILE_B = BNG ? (M_BLK * NOC * 2) : (NOC * M_BLK * 4);
    constexpr int SMEM_B = STAGE_B > TILE_B ? STAGE_B : TILE_B;
    constexpr int HOFF = F32IN ? 1 : 2;
    __shared__ __align__(16) char smem[SMEM_B];
    ushort* stg = (ushort*)smem;

    int bid = xcd_swz(blockIdx.x, gridDim.x);
    const int owt = bid % NOWT; bid /= NOWT;
    const int oh = bid % OH;
    const int b  = bid / OH;
    const int ow0 = owt * M_BLK;
    const int tid = threadIdx.x;
    const int w = tid >> 6, l = tid & 63;
    const int wn = w % NWN, wm = w / NWN;
    const int m_wave = wm * 32, n_wave = wn * 32;
    const int lc = l & 15, lr = l >> 4;

    if (F32IN) {
        constexpr int NG = (SPAN + 6) / 4 + 1;
        const int iwb_al = (ow0 * ST - 2) & ~3;
        const float* inf = (const float*)in_;
        for (int u = tid; u < NR * NG; u += NT) {
            int r = u / NG, gi = u - r * NG;
            int ih = oh * 2 - PH + r;
            int iw4 = iwb_al + gi * 4;
            int q = gi * 4;
            bool rowok = (unsigned)ih < (unsigned)IH;
            if (rowok && iw4 >= 0 && iw4 + 3 < IWE) {
                float4 v = *(const float4*)&inf[((size_t)b * IH + ih) * IWE + iw4];
                ushort4 h;
                h.x = f2bf(v.x); h.y = f2bf(v.y); h.z = f2bf(v.z); h.w = f2bf(v.w);
                *(ushort4*)&stg[r * SSTR + q] = h;
            } else {
#pragma unroll
                for (int j = 0; j < 4; ++j) {
                    int iw = iw4 + j;
                    float v = (rowok && (unsigned)iw < (unsigned)IWE)
                        ? inf[((size_t)b * IH + ih) * IWE + iw] : 0.f;
                    stg[r * SSTR + q + j] = f2bf(v);
                }
            }
        }
    } else {
        constexpr int SPANU = SPAN / 2;
        constexpr int NGU = (SPANU + 6) / 4 + 1;
        const int iub_al = (ow0 - 2) & ~3;
        const uint* inu = (const uint*)in_;
        for (int u = tid; u < NR * NGU; u += NT) {
            int r = u / NGU, gi = u - r * NGU;
            int ih = oh * 2 - PH + r;
            int iu4 = iub_al + gi * 4;
            bool rowok = (unsigned)ih < (unsigned)IH;
            if (rowok && iu4 >= 0 && iu4 + 3 < IWE) {
                uint4 v = *(const uint4*)&inu[((size_t)b * IH + ih) * IWE + iu4];
                *(uint4*)&stg[r * SSTR + gi * 8] = v;
            } else {
#pragma unroll
                for (int j = 0; j < 4; ++j) {
                    int iu = iu4 + j;
                    uint v = (rowok && (unsigned)iu < (unsigned)IWE)
                        ? inu[((size_t)b * IH + ih) * IWE + iu] : 0u;
                    *(uint*)&stg[r * SSTR + gi * 8 + j * 2] = v;
                }
            }
        }
    }

    short8_t bfr[NCH][2];
    {
        const ushort* wb = wp + (size_t)(n_wave + lc) * (NCH * 32) + lr * 8;
#pragma unroll
        for (int cc = 0; cc < NCH; ++cc)
#pragma unroll
            for (int nj = 0; nj < 2; ++nj)
                bfr[cc][nj] = *(const short8_t*)(wb + (size_t)nj * 16 * (NCH * 32) + cc * 32);
    }

    __syncthreads();

    f32x4 acc[2][2];
#pragma unroll
    for (int i = 0; i < 2; ++i)
#pragma unroll
        for (int j = 0; j < 2; ++j) acc[i][j] = (f32x4){0.f, 0.f, 0.f, 0.f};

#pragma unroll
    for (int cc = 0; cc < NCH; ++cc) {
        const int kh = 2 * cc + (lr >> 1);
        const uint* lrow = (const uint*)&stg[kh * SSTR];
        short8_t a[2];
#pragma unroll
        for (int mi = 0; mi < 2; ++mi) {
            const int m = m_wave + mi * 16 + lc;
            const int half = ((m * ST + (lr & 1) * 8) >> 1) + HOFF;
            union { uint u[4]; short8_t s; } av;
            av.u[0] = lrow[half];
            av.u[1] = lrow[half + 1];
            av.u[2] = lrow[half + 2];
            av.u[3] = lrow[half + 3];
            a[mi] = av.s;
        }
#pragma unroll
        for (int mi = 0; mi < 2; ++mi)
#pragma unroll
            for (int nj = 0; nj < 2; ++nj)
                acc[mi][nj] = __builtin_amdgcn_mfma_f32_16x16x32_bf16(a[mi], bfr[cc][nj], acc[mi][nj], 0, 0, 0);
    }

    __syncthreads();

    if (BNG) {
        ushort* tile = (ushort*)smem;
#pragma unroll
        for (int nj = 0; nj < 2; ++nj) {
            const int n = n_wave + nj * 16 + lc;
            const float s = gamma[n] * rsqrtf(1.0f + 1e-5f);
            const float bb = beta[n];
#pragma unroll
            for (int mi = 0; mi < 2; ++mi)
#pragma unroll
                for (int r = 0; r < 4; ++r) {
                    const int m = m_wave + mi * 16 + lr * 4 + r;
                    float y = gelu_erf(fmaf(acc[mi][nj][r], s, bb));
                    tile[m * NOC + n] = f2bf(y);
                }
        }
        __syncthreads();
        const int mv = min(M_BLK, OW - ow0);
        uint* dst = (uint*)((ushort*)out_ + (((size_t)b * OH + oh) * OW + ow0) * NOC);
        const uint* src = (const uint*)tile;
        for (int idx = tid; idx < mv * NOC / 2; idx += NT) dst[idx] = src[idx];
    } else {
        float* tile = (float*)smem;
#pragma unroll
        for (int nj = 0; nj < 2; ++nj) {
            const int n = n_wave + nj * 16 + lc;
#pragma unroll
            for (int mi = 0; mi < 2; ++mi)
#pragma unroll
                for (int r = 0; r < 4; ++r) {
                    const int m = m_wave + mi * 16 + lr * 4 + r;
                    tile[n * M_BLK + m] = acc[mi][nj][r];
                }
        }
        __syncthreads();
        const int mv = min(M_BLK, OW - ow0);
        float* outb = (float*)out_ + ((size_t)b * NOC * OH + oh) * OW + ow0;
        for (int idx = tid; idx < NOC * mv; idx += NT) {
            int oc = idx / mv, j = idx - oc * mv;
            outb[(size_t)oc * OH * OW + j] = tile[oc * M_BLK + j];
        }
    }
}

// ---------- conv2/conv3: full-K implicit-GEMM body (device template), counted vmcnt ----------
// Non-template __global__ wrappers below force instantiation + stub emission.
template <int M_BLK, int NOC, int ICT, int HALVES, int OHPB, int NCH, int NWM, int NWN>
DEV void convgemm_body(
    const ushort* __restrict__ in, const ushort* __restrict__ wp,
    const float* __restrict__ gamma, const float* __restrict__ beta,
    const ushort* __restrict__ zp, ushort* __restrict__ out,
    int IH, int IW, int OH, int OW, int NBLK)
{
    constexpr int NT = 128;
    constexpr int MI = M_BLK / (16 * NWM);
    constexpr int NJ = NOC / (16 * NWN);
    constexpr int KTOT = 75 * ICT;
    constexpr int AU = M_BLK * 4 / NT;
    constexpr int BU = NOC * 4 / NT;
    constexpr int OWS = M_BLK / OHPB;
    static_assert(AU + BU == 6, "vmcnt counts assume 6 loads/chunk");

    __shared__ __align__(16) ushort Abuf[3][M_BLK * 32];
    __shared__ __align__(16) ushort Bbuf[3][NOC * 32];

    int bid = xcd_swz(blockIdx.x, gridDim.x);
    const int oh0 = (bid % NBLK) * OHPB;
    const int b   = bid / NBLK;
    const int tid = threadIdx.x;
    const int w = tid >> 6, l = tid & 63;
    const int wn = w % NWN, wm = w / NWN;
    const int m_wave = wm * 16 * MI, n_wave = wn * 16 * NJ;
    const int lc = l & 15, lr = l >> 4;

    int aih[AU], aiw[AU];
    const ushort* aptr[AU];
#pragma unroll
    for (int i = 0; i < AU; ++i) {
        int u = tid + i * NT;
        int row = u >> 2, slot = u & 3;
        int part = slot ^ ((row ^ (row >> 2)) & 3);
        int ohp = row / OWS, owr = row - ohp * OWS;
        aih[i] = (oh0 + ohp) * 2 - 2;
        aiw[i] = owr * 4 - 2;
        aptr[i] = in + (size_t)b * IH * IW * ICT + part * 8;
    }
    const ushort* bptr[BU];
#pragma unroll
    for (int i = 0; i < BU; ++i) {
        int v = tid + i * NT;
        int row = v >> 2, slot = v & 3;
        int part = slot ^ ((row ^ (row >> 2)) & 3);
        bptr[i] = wp + (size_t)row * KTOT + part * 8;
    }

    auto stage = [&](int kc, int buf) {
        const int tap = (HALVES == 2) ? (kc >> 1) : kc;
        const int kh = tap / 15, kw = tap - kh * 15;
        const int ico = (HALVES == 2) ? (kc & 1) * 32 : 0;
#pragma unroll
        for (int i = 0; i < AU; ++i) {
            int ih = aih[i] + kh, iw = aiw[i] + kw;
            const ushort* src = ((unsigned)ih < (unsigned)IH && (unsigned)iw < (unsigned)IW)
                ? aptr[i] + ((size_t)ih * IW + iw) * ICT + ico : zp;
            __builtin_amdgcn_global_load_lds(src, &Abuf[buf][(tid + i * NT) * 8], 16, 0, 0);
        }
#pragma unroll
        for (int i = 0; i < BU; ++i)
            __builtin_amdgcn_global_load_lds(bptr[i] + kc * 32, &Bbuf[buf][(tid + i * NT) * 8], 16, 0, 0);
    };

    f32x4 acc[MI][NJ];
#pragma unroll
    for (int i = 0; i < MI; ++i)
#pragma unroll
        for (int j = 0; j < NJ; ++j) acc[i][j] = (f32x4){0.f, 0.f, 0.f, 0.f};

    auto compute = [&](int buf) {
        short8_t a[MI], bq[NJ];
#pragma unroll
        for (int mi = 0; mi < MI; ++mi) {
            int row = m_wave + mi * 16 + lc;
            int sl = lr ^ ((row ^ (row >> 2)) & 3);
            a[mi] = *(const short8_t*)&Abuf[buf][row * 32 + sl * 8];
        }
#pragma unroll
        for (int nj = 0; nj < NJ; ++nj) {
            int row = n_wave + nj * 16 + lc;
            int sl = lr ^ ((row ^ (row >> 2)) & 3);
            bq[nj] = *(const short8_t*)&Bbuf[buf][row * 32 + sl * 8];
        }
#pragma unroll
        for (int mi = 0; mi < MI; ++mi)
#pragma unroll
            for (int nj = 0; nj < NJ; ++nj)
                acc[mi][nj] = __builtin_amdgcn_mfma_f32_16x16x32_bf16(a[mi], bq[nj], acc[mi][nj], 0, 0, 0);
    };

    stage(0, 0); stage(1, 1); stage(2, 2);   // 18 loads in flight
    int buf = 0;
#pragma unroll 1
    for (int kc = 0; kc < NCH - 3; ++kc) {
        asm volatile("s_waitcnt vmcnt(12)" ::: "memory");   // chunk kc landed
        __syncthreads();
        compute(buf);
        __syncthreads();
        stage(kc + 3, buf);
        buf = (buf == 2) ? 0 : buf + 1;
    }
    asm volatile("s_waitcnt vmcnt(12)" ::: "memory"); __syncthreads(); compute(buf); buf = (buf == 2) ? 0 : buf + 1;
    asm volatile("s_waitcnt vmcnt(6)" ::: "memory");  __syncthreads(); compute(buf); buf = (buf == 2) ? 0 : buf + 1;
    asm volatile("s_waitcnt vmcnt(0)" ::: "memory");  __syncthreads(); compute(buf);

    // epilogue: BN + GELU, NHWC bf16
#pragma unroll
    for (int nj = 0; nj < NJ; ++nj) {
        const int n = n_wave + nj * 16 + lc;
        const float s = gamma[n] * rsqrtf(1.0f + 1e-5f);
        const float bb = beta[n];
#pragma unroll
        for (int mi = 0; mi < MI; ++mi) {
#pragma unroll
            for (int r = 0; r < 4; ++r) {
                const int m = m_wave + mi * 16 + lr * 4 + r;
                const int ohp = m / OWS, ow = m - ohp * OWS;
                if (ow < OW) {
                    float y = gelu_erf(fmaf(acc[mi][nj][r], s, bb));
                    out[(((size_t)b * OH + oh0 + ohp) * OW + ow) * NOC + n] = f2bf(y);
                }
            }
        }
    }
}

__global__ __launch_bounds__(128) void convgemm2_k(
    const ushort* __restrict__ in, const ushort* __restrict__ wp,
    const float* __restrict__ gamma, const float* __restrict__ beta,
    const ushort* __restrict__ zp, ushort* __restrict__ out,
    int IH, int IW, int OH, int OW, int NBLK)
{
    convgemm_body<128, 64, 32, 1, 1, 75, 2, 1>(in, wp, gamma, beta, zp, out, IH, IW, OH, OW, NBLK);
}

__global__ __launch_bounds__(128) void convgemm3_k(
    const ushort* __restrict__ in, const ushort* __restrict__ wp,
    const float* __restrict__ gamma, const float* __restrict__ beta,
    const ushort* __restrict__ zp, ushort* __restrict__ out,
    int IH, int IW, int OH, int OW, int NBLK)
{
    convgemm_body<64, 128, 64, 2, 2, 150, 1, 2>(in, wp, gamma, beta, zp, out, IH, IW, OH, OW, NBLK);
}

// ---------- conv4: implicit-im2col MFMA GEMM, split-K x8 ----------
__global__ __launch_bounds__(256) void gemm4_k(
    const ushort* __restrict__ h3, const ushort* __restrict__ Bw,
    const ushort* __restrict__ zp, float* __restrict__ part)
{
    __shared__ __align__(16) ushort Al[3][64 * 64];
    __shared__ __align__(16) ushort Bl[3][64 * 64];
    int bid = blockIdx.x;
    const int ks = bid & 7;
    const int nt = (bid >> 3) & 3;
    const int mt = bid >> 5;
    const int m0 = mt * 64, n0 = nt * 64;
    const int k0 = (ks * 150) / 8, k1 = ((ks + 1) * 150) / 8;
    const int tid = threadIdx.x;
    const int w = tid >> 6, l = tid & 63;
    const int wr = (w >> 1) * 32, wc = (w & 1) * 32;
    const int lc = l & 15, lr = l >> 4;

    int ihb[2], iwb[2], bb[2], sspo[2];
    const ushort* gbrow[2];
#pragma unroll
    for (int i = 0; i < 2; ++i) {
        int u = tid + i * 256;
        int row = u >> 3, sl = u & 7;
        int rg = m0 + row;
        int b_ = rg / 25, p = rg - b_ * 25;
        int oh = p / 5, ow = p - oh * 5;
        bb[i] = b_;
        ihb[i] = oh * 2 - 2;
        iwb[i] = ow * 4 - 2;
        sspo[i] = (sl ^ (row & 7)) * 8;
        gbrow[i] = Bw + (size_t)(n0 + row) * 9600 + sspo[i];
    }

    auto stage = [&](int kc, int buf) {
        const int kcp = kc >> 1;
        const int kh = kcp / 15, kw = kcp - kh * 15;
        const int ice = (kc & 1) * 64;
#pragma unroll
        for (int i = 0; i < 2; ++i) {
            const int ih = ihb[i] + kh, iw = iwb[i] + kw;
            const ushort* srcA = ((unsigned)ih < 10u && (unsigned)iw < 28u)
                ? h3 + ((((size_t)bb[i] * 10 + ih) * 28 + iw) << 7) + ice + sspo[i]
                : zp;
            __builtin_amdgcn_global_load_lds(srcA, &Al[buf][(tid + i * 256) * 8], 16, 0, 0);
            __builtin_amdgcn_global_load_lds(gbrow[i] + kc * 64, &Bl[buf][(tid + i * 256) * 8], 16, 0, 0);
        }
    };

    f32x4 acc[2][2];
#pragma unroll
    for (int i = 0; i < 2; ++i)
#pragma unroll
        for (int j = 0; j < 2; ++j) acc[i][j] = (f32x4){0.f, 0.f, 0.f, 0.f};

    auto compute = [&](int buf) {
        short8_t a[2][2], bq[2][2];
#pragma unroll
        for (int mi = 0; mi < 2; ++mi)
#pragma unroll
            for (int ks_ = 0; ks_ < 2; ++ks_) {
                const int row = wr + mi * 16 + lc;
                const int sl = (ks_ * 4 + lr) ^ (row & 7);
                a[mi][ks_] = *(const short8_t*)&Al[buf][row * 64 + sl * 8];
            }
#pragma unroll
        for (int nj = 0; nj < 2; ++nj)
#pragma unroll
            for (int ks_ = 0; ks_ < 2; ++ks_) {
                const int row = wc + nj * 16 + lc;
                const int sl = (ks_ * 4 + lr) ^ (row & 7);
                bq[nj][ks_] = *(const short8_t*)&Bl[buf][row * 64 + sl * 8];
            }
#pragma unroll
        for (int ks_ = 0; ks_ < 2; ++ks_)
#pragma unroll
            for (int mi = 0; mi < 2; ++mi)
#pragma unroll
                for (int nj = 0; nj < 2; ++nj)
                    acc[mi][nj] = __builtin_amdgcn_mfma_f32_16x16x32_bf16(a[mi][ks_], bq[nj][ks_], acc[mi][nj], 0, 0, 0);
    };

    stage(k0, 0); stage(k0 + 1, 1); stage(k0 + 2, 2);
    int buf = 0;
#pragma unroll 1
    for (int kc = k0; kc < k1 - 3; ++kc) {
        asm volatile("s_waitcnt vmcnt(8)" ::: "memory");
        __syncthreads();
        compute(buf);
        __syncthreads();
        stage(kc + 3, buf);
        buf = (buf == 2) ? 0 : buf + 1;
    }
    asm volatile("s_waitcnt vmcnt(8)" ::: "memory"); __syncthreads(); compute(buf); buf = (buf == 2) ? 0 : buf + 1;
    asm volatile("s_waitcnt vmcnt(4)" ::: "memory"); __syncthreads(); compute(buf); buf = (buf == 2) ? 0 : buf + 1;
    asm volatile("s_waitcnt vmcnt(0)" ::: "memory"); __syncthreads(); compute(buf);

    float* dst = part + (size_t)ks * 409600;
#pragma unroll
    for (int mi = 0; mi < 2; ++mi)
#pragma unroll
        for (int nj = 0; nj < 2; ++nj) {
            const int n = n0 + wc + 16 * nj + lc;
#pragma unroll
            for (int r = 0; r < 4; ++r) {
                const int m = m0 + wr + 16 * mi + 4 * lr + r;
                dst[(size_t)m * 256 + n] = acc[mi][nj][r];
            }
        }
}

// ---------- routing head (sums 8 split-K partials, applies conv4's BN+GELU) ----------
__global__ void route_k(const float* __restrict__ part,
                        const float* __restrict__ g4, const float* __restrict__ b4,
                        const float* __restrict__ fw1, const float* __restrict__ fb1,
                        const float* __restrict__ g1d, const float* __restrict__ b1d,
                        const float* __restrict__ fw2, const float* __restrict__ fb2,
                        float* __restrict__ rw_out, int* __restrict__ sel_out)
{
    __shared__ float pooled[256];
    __shared__ float hmid[32];
    __shared__ float rwv[5];
    const int b = blockIdx.x, c = threadIdx.x;
    const float s4 = g4[c] * rsqrtf(1.0f + 1e-5f);
    const float bb4 = b4[c];
    const float* p = part + (size_t)b * 25 * 256 + c;
    float sum = 0.f;
#pragma unroll
    for (int i = 0; i < 25; ++i) {
        float v = 0.f;
#pragma unroll
        for (int j = 0; j < 8; ++j) v += p[i * 256 + j * 409600];
        sum += gelu_erf(fmaf(v, s4, bb4));
    }
    pooled[c] = sum * (1.0f / 25.0f);
    __syncthreads();
    if (c < 32) {
        float a = fb1[c];
        const float* wr = fw1 + c * 256;
        for (int i = 0; i < 256; ++i) a += pooled[i] * wr[i];
        a = gelu_erf(a);
        a = a * (g1d[c] * rsqrtf(1.0f + 1e-5f)) + b1d[c];
        hmid[c] = a;
    }
    __syncthreads();
    if (c < 5) {
        float a = fb2[c];
        const float* wr = fw2 + c * 32;
#pragma unroll
        for (int i = 0; i < 32; ++i) a += hmid[i] * wr[i];
        rwv[c] = a;
        rw_out[b * 5 + c] = a;
    }
    __syncthreads();
    if (c == 0) {
        int i1 = 0;
        for (int i = 1; i < 5; ++i) if (rwv[i] > rwv[i1]) i1 = i;
        int i2 = -1;
        for (int i = 0; i < 5; ++i) {
            if (i == i1) continue;
            if (i2 < 0 || rwv[i] > rwv[i2]) i2 = i;
        }
        sel_out[b * 2]     = i1 < i2 ? i1 : i2;
        sel_out[b * 2 + 1] = i1 < i2 ? i2 : i1;
    }
}

// ---------- gather: 4 idx/thread, aligned float4 loads, uint4 store ----------
__global__ void gather_k(const float* __restrict__ x, const int* __restrict__ sel,
                         uint4* __restrict__ gated)
{
    const int g = blockIdx.x * blockDim.x + threadIdx.x;
    const int idx0 = g * 4;
    const int b = idx0 / 32000;
    const int s0 = sel[b * 2], s1 = sel[b * 2 + 1];
    const float* xp = x + (size_t)idx0 * 5;
    float4 v0 = *(const float4*)(xp);
    float4 v1 = *(const float4*)(xp + 4);
    float4 v2 = *(const float4*)(xp + 8);
    float4 v3 = *(const float4*)(xp + 12);
    float4 v4 = *(const float4*)(xp + 16);
    float vals[5][4];
    vals[0][0] = v0.x; vals[1][0] = v0.y; vals[2][0] = v0.z; vals[3][0] = v0.w; vals[4][0] = v1.x;
    vals[0][1] = v1.y; vals[1][1] = v1.z; vals[2][1] = v1.w; vals[3][1] = v2.x; vals[4][1] = v2.y;
    vals[0][2] = v2.z; vals[1][2] = v2.w; vals[2][2] = v3.x; vals[3][2] = v3.y; vals[4][2] = v3.z;
    vals[0][3] = v3.w; vals[1][3] = v4.x; vals[2][3] = v4.y; vals[3][3] = v4.z; vals[4][3] = v4.w;
    uint out[4];
#pragma unroll
    for (int j = 0; j < 4; ++j) {
        float lo = vals[0][j];
        lo = (s0 == 1) ? vals[1][j] : lo;
        lo = (s0 == 2) ? vals[2][j] : lo;
        lo = (s0 == 3) ? vals[3][j] : lo;
        lo = (s0 == 4) ? vals[4][j] : lo;
        float hi = vals[0][j];
        hi = (s1 == 1) ? vals[1][j] : hi;
        hi = (s1 == 2) ? vals[2][j] : hi;
        hi = (s1 == 3) ? vals[3][j] : hi;
        hi = (s1 == 4) ? vals[4][j] : hi;
        out[j] = (uint)f2bf(lo) | ((uint)f2bf(hi) << 16);
    }
    gated[g] = (uint4){out[0], out[1], out[2], out[3]};
}

extern "C" void kernel_launch(void* const* d_in, const int* in_sizes, int n_in,
                              void* d_out, int out_size, void* d_ws, size_t ws_size,
                              hipStream_t stream)
{
    const float* x     = (const float*)d_in[0];
    const float* total = (const float*)d_in[1];
    const float* gw1 = (const float*)d_in[2];
    const float* g1  = (const float*)d_in[3];
    const float* b1  = (const float*)d_in[4];
    const float* gw2 = (const float*)d_in[5];
    const float* g2  = (const float*)d_in[6];
    const float* b2  = (const float*)d_in[7];
    const float* gw3 = (const float*)d_in[8];
    const float* g3  = (const float*)d_in[9];
    const float* b3  = (const float*)d_in[10];
    const float* gw4 = (const float*)d_in[11];
    const float* g4  = (const float*)d_in[12];
    const float* b4  = (const float*)d_in[13];
    const float* fw1 = (const float*)d_in[14];
    const float* fb1 = (const float*)d_in[15];
    const float* g1d = (const float*)d_in[16];
    const float* b1d = (const float*)d_in[17];
    const float* fw2 = (const float*)d_in[18];
    const float* fb2 = (const float*)d_in[19];
    const float* cw1 = (const float*)d_in[20];

    char* ws = (char*)d_ws;
    size_t off = 0;
    auto alloc = [&](size_t bytes) { void* p = ws + off; off = (off + bytes + 255) & ~(size_t)255; return p; };
    ushort* h1n = (ushort*)alloc((size_t)40796160 * 2); // NHWC [64][40][498][32]
    ushort* h2n = (ushort*)alloc((size_t)9994240 * 2);  // NHWC [64][20][122][64]
    ushort* h3n = (ushort*)alloc((size_t)2293760 * 2);  // NHWC [64][10][28][128]
    float* part  = (float*)alloc((size_t)8 * 409600 * 4); // split-K partials [8][1600][256]
    int*   sel   = (int*)alloc(512);
    uint*  gated = (uint*)alloc((size_t)2048000 * 4);   // [64][80][400] packed bf16x2
    ushort* wp1 = (ushort*)alloc((size_t)3072 * 2);
    ushort* wp2 = (ushort*)alloc((size_t)153600 * 2);   // [64][2400] k-contig
    ushort* wp3 = (ushort*)alloc((size_t)614400 * 2);   // [128][4800] k-contig
    ushort* w4p = (ushort*)alloc((size_t)2457600 * 2);  // [256][9600]
    ushort* wp5 = (ushort*)alloc((size_t)8192 * 2);
    ushort* zp  = (ushort*)alloc(512);                  // zero page

    float* outc = (float*)d_out;            // [64,64,40,397]
    float* rw   = outc + (size_t)65044480;  // [64,5]

    // weight prep (449 blocks)
    prep_k<<<449, 256, 0, stream>>>(gw1, gw2, gw3, gw4, cw1, wp1, wp2, wp3, w4p, wp5, zp);

    // L1: MFMA IC=1 conv (grid 10240)
    convmm1_k<128, 32, 3, 4, 1, 4, true, true><<<64 * 40 * 4, 256, 0, stream>>>(
        total, wp1, g1, b1, h1n, 80, 2000, 40, 498, 4, 2);

    // L2: convgemm — M_BLK=128 (full row), NOC=64, ICT=32, 75 chunks, waves 2x1 (grid 1280)
    convgemm2_k<<<64 * 20, 128, 0, stream>>>(
        h1n, wp2, g2, b2, zp, h2n, 40, 498, 20, 122, 20);

    // L3: convgemm — M_BLK=64 (2 oh x 32), NOC=128, ICT=64, 150 chunks, waves 1x2 (grid 320)
    convgemm3_k<<<64 * 5, 128, 0, stream>>>(
        h2n, wp3, g3, b3, zp, h3n, 20, 122, 10, 28, 5);

    // L4: implicit-im2col MFMA GEMM, split-K x8 (grid 800)
    gemm4_k<<<800, 256, 0, stream>>>(h3n, w4p, zp, part);

    // routing head
    route_k<<<64, 256, 0, stream>>>(part, g4, b4, fw1, fb1, g1d, b1d, fw2, fb2, rw, sel);

    // gather
    gather_k<<<2000, 256, 0, stream>>>(x, sel, (uint4*)gated);

    // L5: MFMA IC=1 conv via (t,s) factorization (grid 17920)
    convmm1_k<64, 64, 4, 2, 2, 2, false, false><<<64 * 40 * 7, 256, 0, stream>>>(
        gated, wp5, nullptr, nullptr, outc, 80, 400, 40, 397, 7, 3);
}

// Round 15
// 423.142 us; speedup vs baseline: 1.5365x; 1.5365x over previous
//
#include <hip/hip_runtime.h>
#include <hip/hip_bf16.h>

#define DEV __device__ __forceinline__

typedef __attribute__((ext_vector_type(8))) short short8_t;
typedef __attribute__((ext_vector_type(4))) float f32x4;

DEV float gelu_erf(float x) { return 0.5f * x * (1.0f + erff(x * 0.70710678118654752440f)); }
DEV ushort f2bf(float v) { __hip_bfloat16 h = __float2bfloat16(v); return *(ushort*)&h; }

// XCD-aware bijective swizzle (grid must be a multiple of 8)
DEV int xcd_swz(int bid, int nwg) {
    int q = nwg >> 3;
    return (bid & 7) * q + (bid >> 3);
}

// ---------- fused weight prep + zeropage ----------
__global__ void prep_k(const float* __restrict__ gw1, const float* __restrict__ gw2,
                       const float* __restrict__ gw3, const float* __restrict__ gw4,
                       const float* __restrict__ cw1,
                       ushort* __restrict__ wp1, ushort* __restrict__ wp2,
                       ushort* __restrict__ wp3, ushort* __restrict__ w4p,
                       ushort* __restrict__ wp5, ushort* __restrict__ zp)
{
    int idx = blockIdx.x * blockDim.x + threadIdx.x;
    if (idx < 2457600) {            // gw4 [256][128][75] -> w4p [256][(kh*15+kw)*128+ic]
        int kp = idx % 9600, oc = idx / 9600;
        int ic = kp & 127, kc = kp >> 7;
        w4p[idx] = f2bf(gw4[((size_t)oc * 128 + ic) * 75 + kc]);
        return;
    }
    idx -= 2457600;
    if (idx < 614400) {             // gw3 -> wp3 [75][128][64]
        int ic = idx % 64, t = idx / 64;
        int oc = t % 128, kc = t / 128;
        wp3[idx] = f2bf(gw3[((size_t)oc * 64 + ic) * 75 + kc]);
        return;
    }
    idx -= 614400;
    if (idx < 153600) {             // gw2 -> wp2 [75][64][32]
        int ic = idx % 32, t = idx / 32;
        int oc = t % 64, kc = t / 64;
        wp2[idx] = f2bf(gw2[((size_t)oc * 32 + ic) * 75 + kc]);
        return;
    }
    idx -= 153600;
    if (idx < 8192) {               // cw1 [64][98] -> wp5[64][128]
        int oc = idx >> 7, k = idx & 127;
        int kh = k >> 4, t = k & 15;
        int a = t >> 1, c = t & 1, kw = 2 * a + c - 1;
        float v = (kh < 7 && kw >= 0 && kw < 14) ? cw1[oc * 98 + kh * 14 + kw] : 0.f;
        wp5[idx] = f2bf(v);
        return;
    }
    idx -= 8192;
    if (idx < 3072) {               // gw1 [32][75] -> wp1[32][96]
        int oc = idx / 96, k = idx % 96;
        int kh = k >> 4, kw = k & 15;
        float v = (kh < 5 && kw < 15) ? gw1[oc * 75 + kh * 15 + kw] : 0.f;
        wp1[idx] = f2bf(v);
        return;
    }
    idx -= 3072;
    zp[idx] = 0;
}

// ---------- IC=1 implicit-GEMM MFMA conv (conv1, conv5) ----------
template <int M_BLK, int NOC, int NCH, int NWM, int NWN, int ST, bool F32IN, bool BNG>
__global__ __launch_bounds__(64 * NWM * NWN) void convmm1_k(
    const void* __restrict__ in_, const ushort* __restrict__ wp,
    const float* __restrict__ gamma, const float* __restrict__ beta,
    void* __restrict__ out_,
    int IH, int IWE, int OH, int OW, int NOWT, int PH)
{
    constexpr int NT = 64 * NWM * NWN;
    constexpr int NR = 2 * NCH;
    constexpr int SPAN = (M_BLK - 1) * ST + 16;
    constexpr int SSTR = ((SPAN + 16 + 7) & ~7) + 8;
    constexpr int STAGE_B = NR * SSTR * 2;
    constexpr int TILE_B = BNG ? (M_BLK * NOC * 2) : (NOC * M_BLK * 4);
    constexpr int SMEM_B = STAGE_B > TILE_B ? STAGE_B : TILE_B;
    constexpr int HOFF = F32IN ? 1 : 2;
    __shared__ __align__(16) char smem[SMEM_B];
    ushort* stg = (ushort*)smem;

    int bid = xcd_swz(blockIdx.x, gridDim.x);
    const int owt = bid % NOWT; bid /= NOWT;
    const int oh = bid % OH;
    const int b  = bid / OH;
    const int ow0 = owt * M_BLK;
    const int tid = threadIdx.x;
    const int w = tid >> 6, l = tid & 63;
    const int wn = w % NWN, wm = w / NWN;
    const int m_wave = wm * 32, n_wave = wn * 32;
    const int lc = l & 15, lr = l >> 4;

    if (F32IN) {
        constexpr int NG = (SPAN + 6) / 4 + 1;
        const int iwb_al = (ow0 * ST - 2) & ~3;
        const float* inf = (const float*)in_;
        for (int u = tid; u < NR * NG; u += NT) {
            int r = u / NG, gi = u - r * NG;
            int ih = oh * 2 - PH + r;
            int iw4 = iwb_al + gi * 4;
            int q = gi * 4;
            bool rowok = (unsigned)ih < (unsigned)IH;
            if (rowok && iw4 >= 0 && iw4 + 3 < IWE) {
                float4 v = *(const float4*)&inf[((size_t)b * IH + ih) * IWE + iw4];
                ushort4 h;
                h.x = f2bf(v.x); h.y = f2bf(v.y); h.z = f2bf(v.z); h.w = f2bf(v.w);
                *(ushort4*)&stg[r * SSTR + q] = h;
            } else {
#pragma unroll
                for (int j = 0; j < 4; ++j) {
                    int iw = iw4 + j;
                    float v = (rowok && (unsigned)iw < (unsigned)IWE)
                        ? inf[((size_t)b * IH + ih) * IWE + iw] : 0.f;
                    stg[r * SSTR + q + j] = f2bf(v);
                }
            }
        }
    } else {
        constexpr int SPANU = SPAN / 2;
        constexpr int NGU = (SPANU + 6) / 4 + 1;
        const int iub_al = (ow0 - 2) & ~3;
        const uint* inu = (const uint*)in_;
        for (int u = tid; u < NR * NGU; u += NT) {
            int r = u / NGU, gi = u - r * NGU;
            int ih = oh * 2 - PH + r;
            int iu4 = iub_al + gi * 4;
            bool rowok = (unsigned)ih < (unsigned)IH;
            if (rowok && iu4 >= 0 && iu4 + 3 < IWE) {
                uint4 v = *(const uint4*)&inu[((size_t)b * IH + ih) * IWE + iu4];
                *(uint4*)&stg[r * SSTR + gi * 8] = v;
            } else {
#pragma unroll
                for (int j = 0; j < 4; ++j) {
                    int iu = iu4 + j;
                    uint v = (rowok && (unsigned)iu < (unsigned)IWE)
                        ? inu[((size_t)b * IH + ih) * IWE + iu] : 0u;
                    *(uint*)&stg[r * SSTR + gi * 8 + j * 2] = v;
                }
            }
        }
    }

    short8_t bfr[NCH][2];
    {
        const ushort* wb = wp + (size_t)(n_wave + lc) * (NCH * 32) + lr * 8;
#pragma unroll
        for (int cc = 0; cc < NCH; ++cc)
#pragma unroll
            for (int nj = 0; nj < 2; ++nj)
                bfr[cc][nj] = *(const short8_t*)(wb + (size_t)nj * 16 * (NCH * 32) + cc * 32);
    }

    __syncthreads();

    f32x4 acc[2][2];
#pragma unroll
    for (int i = 0; i < 2; ++i)
#pragma unroll
        for (int j = 0; j < 2; ++j) acc[i][j] = (f32x4){0.f, 0.f, 0.f, 0.f};

#pragma unroll
    for (int cc = 0; cc < NCH; ++cc) {
        const int kh = 2 * cc + (lr >> 1);
        const uint* lrow = (const uint*)&stg[kh * SSTR];
        short8_t a[2];
#pragma unroll
        for (int mi = 0; mi < 2; ++mi) {
            const int m = m_wave + mi * 16 + lc;
            const int half = ((m * ST + (lr & 1) * 8) >> 1) + HOFF;
            union { uint u[4]; short8_t s; } av;
            av.u[0] = lrow[half];
            av.u[1] = lrow[half + 1];
            av.u[2] = lrow[half + 2];
            av.u[3] = lrow[half + 3];
            a[mi] = av.s;
        }
#pragma unroll
        for (int mi = 0; mi < 2; ++mi)
#pragma unroll
            for (int nj = 0; nj < 2; ++nj)
                acc[mi][nj] = __builtin_amdgcn_mfma_f32_16x16x32_bf16(a[mi], bfr[cc][nj], acc[mi][nj], 0, 0, 0);
    }

    __syncthreads();

    if (BNG) {
        ushort* tile = (ushort*)smem;
#pragma unroll
        for (int nj = 0; nj < 2; ++nj) {
            const int n = n_wave + nj * 16 + lc;
            const float s = gamma[n] * rsqrtf(1.0f + 1e-5f);
            const float bb = beta[n];
#pragma unroll
            for (int mi = 0; mi < 2; ++mi)
#pragma unroll
                for (int r = 0; r < 4; ++r) {
                    const int m = m_wave + mi * 16 + lr * 4 + r;
                    float y = gelu_erf(fmaf(acc[mi][nj][r], s, bb));
                    tile[m * NOC + n] = f2bf(y);
                }
        }
        __syncthreads();
        const int mv = min(M_BLK, OW - ow0);
        uint* dst = (uint*)((ushort*)out_ + (((size_t)b * OH + oh) * OW + ow0) * NOC);
        const uint* src = (const uint*)tile;
        for (int idx = tid; idx < mv * NOC / 2; idx += NT) dst[idx] = src[idx];
    } else {
        float* tile = (float*)smem;
#pragma unroll
        for (int nj = 0; nj < 2; ++nj) {
            const int n = n_wave + nj * 16 + lc;
#pragma unroll
            for (int mi = 0; mi < 2; ++mi)
#pragma unroll
                for (int r = 0; r < 4; ++r) {
                    const int m = m_wave + mi * 16 + lr * 4 + r;
                    tile[n * M_BLK + m] = acc[mi][nj][r];
                }
        }
        __syncthreads();
        const int mv = min(M_BLK, OW - ow0);
        float* outb = (float*)out_ + ((size_t)b * NOC * OH + oh) * OW + ow0;
        for (int idx = tid; idx < NOC * mv; idx += NT) {
            int oc = idx / mv, j = idx - oc * mv;
            outb[(size_t)oc * OH * OW + j] = tile[oc * M_BLK + j];
        }
    }
}

// ---------- implicit-GEMM MFMA conv (conv2/conv3), T14 reg-prefetch, single LDS buffer ----------
template <int M_BLK, int OC, int ICT, int NICC, int NWM, int NWN, int UNR>
__global__ __launch_bounds__(64 * NWM * NWN) void convmm_k(
    const ushort* __restrict__ in, const ushort* __restrict__ wp,
    const float* __restrict__ gamma, const float* __restrict__ beta,
    ushort* __restrict__ out,
    int IH, int IW, int OH, int OW, int NOWT)
{
    constexpr int KH = 5, KW = 15, SW = 4;
    constexpr int MI = M_BLK / (16 * NWM);
    constexpr int NJ = OC / (16 * NWN);
    constexpr int SPAN = (M_BLK - 1) * SW + KW;
    constexpr int ICB = ICT * 2;
    constexpr int NSL = ICT / 8;
    constexpr int KEYM = NSL - 1;
    constexpr int NT = 64 * NWM * NWN;
    constexpr int NUNITS = SPAN * NSL;
    constexpr int NLD = (NUNITS + NT - 1) / NT;

    __shared__ __align__(16) ushort Abuf[SPAN * ICT];

    int bid = xcd_swz(blockIdx.x, gridDim.x);
    const int owt = bid % NOWT; bid /= NOWT;
    const int oh  = bid % OH;
    const int b   = bid / OH;
    const int ow0 = owt * M_BLK;
    const int tid = threadIdx.x;
    const int w = tid >> 6, l = tid & 63;
    const int wn = w % NWN, wm = w / NWN;
    const int m_wave = wm * (16 * MI), n_wave = wn * (16 * NJ);
    const int lc = l & 15, lr = l >> 4;

    const int ih0 = oh * 2 - 2;
    const int iw0 = ow0 * SW - 2;
    const ushort* inb = in + (size_t)b * IH * IW * ICT;

    int up[NLD], usl[NLD], uoff[NLD];
    bool uv[NLD];
#pragma unroll
    for (int i = 0; i < NLD; ++i) {
        int u = tid + i * NT;
        uv[i] = u < NUNITS;
        int uu = uv[i] ? u : 0;
        up[i] = uu / NSL;
        usl[i] = uu - up[i] * NSL;
        uoff[i] = up[i] * ICB + ((usl[i] ^ ((up[i] >> 2) & KEYM)) << 4);
    }

    uint4 rg[NLD];
    auto prefetch = [&](int kh) {
        const int ih = ih0 + kh;
        const bool rowok = (unsigned)ih < (unsigned)IH;
        const ushort* src = inb + (size_t)ih * IW * ICT;
#pragma unroll
        for (int i = 0; i < NLD; ++i) {
            int iw = iw0 + up[i];
            uint4 v = {0u, 0u, 0u, 0u};
            if (rowok && uv[i] && (unsigned)iw < (unsigned)IW)
                v = *(const uint4*)(src + (size_t)iw * ICT + usl[i] * 8);
            rg[i] = v;
        }
    };
    auto writestage = [&]() {
#pragma unroll
        for (int i = 0; i < NLD; ++i)
            if (uv[i]) *(uint4*)((char*)Abuf + uoff[i]) = rg[i];
    };

    f32x4 acc[MI][NJ];
#pragma unroll
    for (int i = 0; i < MI; ++i)
#pragma unroll
        for (int j = 0; j < NJ; ++j) acc[i][j] = (f32x4){0.f, 0.f, 0.f, 0.f};

    prefetch(0);
    writestage();
    __syncthreads();

#pragma unroll 1
    for (int kh = 0; kh < KH; ++kh) {
        if (kh + 1 < KH) prefetch(kh + 1);
        const char* buf = (const char*)Abuf;
        const ushort* wkh = wp + (size_t)(kh * KW) * OC * ICT + (size_t)(n_wave + lc) * ICT + lr * 8;
#pragma unroll UNR
        for (int kw = 0; kw < KW; ++kw) {
#pragma unroll
            for (int icc = 0; icc < NICC; ++icc) {
                short8_t a[MI], bf[NJ];
#pragma unroll
                for (int mi = 0; mi < MI; ++mi) {
                    const int r = m_wave + mi * 16 + lc;
                    const int p = SW * r + kw;
                    const int sl = icc * 4 + lr;
                    a[mi] = *(const short8_t*)(buf + p * ICB + ((sl ^ ((p >> 2) & KEYM)) << 4));
                }
                const ushort* wb = wkh + (size_t)kw * OC * ICT + icc * 32;
#pragma unroll
                for (int nj = 0; nj < NJ; ++nj)
                    bf[nj] = *(const short8_t*)(wb + (size_t)nj * 16 * ICT);
#pragma unroll
                for (int mi = 0; mi < MI; ++mi)
#pragma unroll
                    for (int nj = 0; nj < NJ; ++nj)
                        acc[mi][nj] = __builtin_amdgcn_mfma_f32_16x16x32_bf16(a[mi], bf[nj], acc[mi][nj], 0, 0, 0);
            }
        }
        if (kh + 1 < KH) {
            __syncthreads();
            writestage();
            __syncthreads();
        }
    }

    ushort* outb = out + ((size_t)b * OH + oh) * OW * OC;
#pragma unroll
    for (int nj = 0; nj < NJ; ++nj) {
        const int n = n_wave + nj * 16 + lc;
        const float s = gamma[n] * rsqrtf(1.0f + 1e-5f);
        const float bb = beta[n];
#pragma unroll
        for (int mi = 0; mi < MI; ++mi) {
#pragma unroll
            for (int r = 0; r < 4; ++r) {
                const int m = m_wave + mi * 16 + lr * 4 + r;
                const int ow = ow0 + m;
                if (ow < OW) {
                    float y = gelu_erf(fmaf(acc[mi][nj][r], s, bb));
                    outb[(size_t)ow * OC + n] = f2bf(y);
                }
            }
        }
    }
}

// ---------- conv4: implicit-im2col MFMA GEMM, split-K x4 ----------
__global__ __launch_bounds__(256) void gemm4_k(
    const ushort* __restrict__ h3, const ushort* __restrict__ Bw,
    const ushort* __restrict__ zp, float* __restrict__ part)
{
    __shared__ __align__(16) ushort Al[3][64 * 64];
    __shared__ __align__(16) ushort Bl[3][64 * 64];
    int bid = blockIdx.x;
    const int ks = bid & 3;
    const int nt = (bid >> 2) & 3;
    const int mt = bid >> 4;
    const int m0 = mt * 64, n0 = nt * 64;
    const int k0 = (ks * 150) / 4, k1 = ((ks + 1) * 150) / 4;
    const int tid = threadIdx.x;
    const int w = tid >> 6, l = tid & 63;
    const int wr = (w >> 1) * 32, wc = (w & 1) * 32;
    const int lc = l & 15, lr = l >> 4;

    int ihb[2], iwb[2], bb[2], sspo[2];
    const ushort* gbrow[2];
#pragma unroll
    for (int i = 0; i < 2; ++i) {
        int u = tid + i * 256;
        int row = u >> 3, sl = u & 7;
        int rg = m0 + row;
        int b_ = rg / 25, p = rg - b_ * 25;
        int oh = p / 5, ow = p - oh * 5;
        bb[i] = b_;
        ihb[i] = oh * 2 - 2;
        iwb[i] = ow * 4 - 2;
        sspo[i] = (sl ^ (row & 7)) * 8;
        gbrow[i] = Bw + (size_t)(n0 + row) * 9600 + sspo[i];
    }

    auto stage = [&](int kc, int buf) {
        const int kcp = kc >> 1;
        const int kh = kcp / 15, kw = kcp - kh * 15;
        const int ice = (kc & 1) * 64;
#pragma unroll
        for (int i = 0; i < 2; ++i) {
            const int ih = ihb[i] + kh, iw = iwb[i] + kw;
            const ushort* srcA = ((unsigned)ih < 10u && (unsigned)iw < 28u)
                ? h3 + ((((size_t)bb[i] * 10 + ih) * 28 + iw) << 7) + ice + sspo[i]
                : zp;
            __builtin_amdgcn_global_load_lds(srcA, &Al[buf][(tid + i * 256) * 8], 16, 0, 0);
            __builtin_amdgcn_global_load_lds(gbrow[i] + kc * 64, &Bl[buf][(tid + i * 256) * 8], 16, 0, 0);
        }
    };

    f32x4 acc[2][2];
#pragma unroll
    for (int i = 0; i < 2; ++i)
#pragma unroll
        for (int j = 0; j < 2; ++j) acc[i][j] = (f32x4){0.f, 0.f, 0.f, 0.f};

    auto compute = [&](int buf) {
        short8_t a[2][2], bq[2][2];
#pragma unroll
        for (int mi = 0; mi < 2; ++mi)
#pragma unroll
            for (int ks_ = 0; ks_ < 2; ++ks_) {
                const int row = wr + mi * 16 + lc;
                const int sl = (ks_ * 4 + lr) ^ (row & 7);
                a[mi][ks_] = *(const short8_t*)&Al[buf][row * 64 + sl * 8];
            }
#pragma unroll
        for (int nj = 0; nj < 2; ++nj)
#pragma unroll
            for (int ks_ = 0; ks_ < 2; ++ks_) {
                const int row = wc + nj * 16 + lc;
                const int sl = (ks_ * 4 + lr) ^ (row & 7);
                bq[nj][ks_] = *(const short8_t*)&Bl[buf][row * 64 + sl * 8];
            }
#pragma unroll
        for (int ks_ = 0; ks_ < 2; ++ks_)
#pragma unroll
            for (int mi = 0; mi < 2; ++mi)
#pragma unroll
                for (int nj = 0; nj < 2; ++nj)
                    acc[mi][nj] = __builtin_amdgcn_mfma_f32_16x16x32_bf16(a[mi][ks_], bq[nj][ks_], acc[mi][nj], 0, 0, 0);
    };

    stage(k0, 0); stage(k0 + 1, 1); stage(k0 + 2, 2);
    int buf = 0;
#pragma unroll 1
    for (int kc = k0; kc < k1 - 3; ++kc) {
        asm volatile("s_waitcnt vmcnt(8)" ::: "memory");
        __syncthreads();
        compute(buf);
        __syncthreads();
        stage(kc + 3, buf);
        buf = (buf == 2) ? 0 : buf + 1;
    }
    asm volatile("s_waitcnt vmcnt(8)" ::: "memory"); __syncthreads(); compute(buf); buf = (buf == 2) ? 0 : buf + 1;
    asm volatile("s_waitcnt vmcnt(4)" ::: "memory"); __syncthreads(); compute(buf); buf = (buf == 2) ? 0 : buf + 1;
    asm volatile("s_waitcnt vmcnt(0)" ::: "memory"); __syncthreads(); compute(buf);

    float* dst = part + (size_t)ks * 409600;
#pragma unroll
    for (int mi = 0; mi < 2; ++mi)
#pragma unroll
        for (int nj = 0; nj < 2; ++nj) {
            const int n = n0 + wc + 16 * nj + lc;
#pragma unroll
            for (int r = 0; r < 4; ++r) {
                const int m = m0 + wr + 16 * mi + 4 * lr + r;
                dst[(size_t)m * 256 + n] = acc[mi][nj][r];
            }
        }
}

// ---------- routing head (sums split-K partials, applies conv4's BN+GELU) ----------
__global__ void route_k(const float* __restrict__ part,
                        const float* __restrict__ g4, const float* __restrict__ b4,
                        const float* __restrict__ fw1, const float* __restrict__ fb1,
                        const float* __restrict__ g1d, const float* __restrict__ b1d,
                        const float* __restrict__ fw2, const float* __restrict__ fb2,
                        float* __restrict__ rw_out, int* __restrict__ sel_out)
{
    __shared__ float pooled[256];
    __shared__ float hmid[32];
    __shared__ float rwv[5];
    const int b = blockIdx.x, c = threadIdx.x;
    const float s4 = g4[c] * rsqrtf(1.0f + 1e-5f);
    const float bb4 = b4[c];
    const float* p = part + (size_t)b * 25 * 256 + c;
    float sum = 0.f;
#pragma unroll
    for (int i = 0; i < 25; ++i) {
        float v = p[i * 256] + p[409600 + i * 256] + p[819200 + i * 256] + p[1228800 + i * 256];
        sum += gelu_erf(fmaf(v, s4, bb4));
    }
    pooled[c] = sum * (1.0f / 25.0f);
    __syncthreads();
    if (c < 32) {
        float a = fb1[c];
        const float* wr = fw1 + c * 256;
        for (int i = 0; i < 256; ++i) a += pooled[i] * wr[i];
        a = gelu_erf(a);
        a = a * (g1d[c] * rsqrtf(1.0f + 1e-5f)) + b1d[c];
        hmid[c] = a;
    }
    __syncthreads();
    if (c < 5) {
        float a = fb2[c];
        const float* wr = fw2 + c * 32;
#pragma unroll
        for (int i = 0; i < 32; ++i) a += hmid[i] * wr[i];
        rwv[c] = a;
        rw_out[b * 5 + c] = a;
    }
    __syncthreads();
    if (c == 0) {
        int i1 = 0;
        for (int i = 1; i < 5; ++i) if (rwv[i] > rwv[i1]) i1 = i;
        int i2 = -1;
        for (int i = 0; i < 5; ++i) {
            if (i == i1) continue;
            if (i2 < 0 || rwv[i] > rwv[i2]) i2 = i;
        }
        sel_out[b * 2]     = i1 < i2 ? i1 : i2;
        sel_out[b * 2 + 1] = i1 < i2 ? i2 : i1;
    }
}

// ---------- gather: 4 idx/thread, aligned float4 loads, uint4 store ----------
__global__ void gather_k(const float* __restrict__ x, const int* __restrict__ sel,
                         uint4* __restrict__ gated)
{
    const int g = blockIdx.x * blockDim.x + threadIdx.x;
    const int idx0 = g * 4;
    const int b = idx0 / 32000;
    const int s0 = sel[b * 2], s1 = sel[b * 2 + 1];
    const float* xp = x + (size_t)idx0 * 5;
    float4 v0 = *(const float4*)(xp);
    float4 v1 = *(const float4*)(xp + 4);
    float4 v2 = *(const float4*)(xp + 8);
    float4 v3 = *(const float4*)(xp + 12);
    float4 v4 = *(const float4*)(xp + 16);
    float vals[5][4];
    vals[0][0] = v0.x; vals[1][0] = v0.y; vals[2][0] = v0.z; vals[3][0] = v0.w; vals[4][0] = v1.x;
    vals[0][1] = v1.y; vals[1][1] = v1.z; vals[2][1] = v1.w; vals[3][1] = v2.x; vals[4][1] = v2.y;
    vals[0][2] = v2.z; vals[1][2] = v2.w; vals[2][2] = v3.x; vals[3][2] = v3.y; vals[4][2] = v3.z;
    vals[0][3] = v3.w; vals[1][3] = v4.x; vals[2][3] = v4.y; vals[3][3] = v4.z; vals[4][3] = v4.w;
    uint out[4];
#pragma unroll
    for (int j = 0; j < 4; ++j) {
        float lo = vals[0][j];
        lo = (s0 == 1) ? vals[1][j] : lo;
        lo = (s0 == 2) ? vals[2][j] : lo;
        lo = (s0 == 3) ? vals[3][j] : lo;
        lo = (s0 == 4) ? vals[4][j] : lo;
        float hi = vals[0][j];
        hi = (s1 == 1) ? vals[1][j] : hi;
        hi = (s1 == 2) ? vals[2][j] : hi;
        hi = (s1 == 3) ? vals[3][j] : hi;
        hi = (s1 == 4) ? vals[4][j] : hi;
        out[j] = (uint)f2bf(lo) | ((uint)f2bf(hi) << 16);
    }
    gated[g] = (uint4){out[0], out[1], out[2], out[3]};
}

extern "C" void kernel_launch(void* const* d_in, const int* in_sizes, int n_in,
                              void* d_out, int out_size, void* d_ws, size_t ws_size,
                              hipStream_t stream)
{
    const float* x     = (const float*)d_in[0];
    const float* total = (const float*)d_in[1];
    const float* gw1 = (const float*)d_in[2];
    const float* g1  = (const float*)d_in[3];
    const float* b1  = (const float*)d_in[4];
    const float* gw2 = (const float*)d_in[5];
    const float* g2  = (const float*)d_in[6];
    const float* b2  = (const float*)d_in[7];
    const float* gw3 = (const float*)d_in[8];
    const float* g3  = (const float*)d_in[9];
    const float* b3  = (const float*)d_in[10];
    const float* gw4 = (const float*)d_in[11];
    const float* g4  = (const float*)d_in[12];
    const float* b4  = (const float*)d_in[13];
    const float* fw1 = (const float*)d_in[14];
    const float* fb1 = (const float*)d_in[15];
    const float* g1d = (const float*)d_in[16];
    const float* b1d = (const float*)d_in[17];
    const float* fw2 = (const float*)d_in[18];
    const float* fb2 = (const float*)d_in[19];
    const float* cw1 = (const float*)d_in[20];

    char* ws = (char*)d_ws;
    size_t off = 0;
    auto alloc = [&](size_t bytes) { void* p = ws + off; off = (off + bytes + 255) & ~(size_t)255; return p; };
    ushort* h1n = (ushort*)alloc((size_t)40796160 * 2); // NHWC [64][40][498][32]
    ushort* h2n = (ushort*)alloc((size_t)9994240 * 2);  // NHWC [64][20][122][64]
    ushort* h3n = (ushort*)alloc((size_t)2293760 * 2);  // NHWC [64][10][28][128]
    float* part  = (float*)alloc((size_t)4 * 409600 * 4); // split-K partials [4][1600][256]
    int*   sel   = (int*)alloc(512);
    uint*  gated = (uint*)alloc((size_t)2048000 * 4);   // [64][80][400] packed bf16x2
    ushort* wp1 = (ushort*)alloc((size_t)3072 * 2);
    ushort* wp2 = (ushort*)alloc((size_t)153600 * 2);   // [75][64][32]
    ushort* wp3 = (ushort*)alloc((size_t)614400 * 2);   // [75][128][64]
    ushort* w4p = (ushort*)alloc((size_t)2457600 * 2);  // [256][9600]
    ushort* wp5 = (ushort*)alloc((size_t)8192 * 2);
    ushort* zp  = (ushort*)alloc(512);                  // zero page

    float* outc = (float*)d_out;            // [64,64,40,397]
    float* rw   = outc + (size_t)65044480;  // [64,5]

    // fused weight prep + zeropage
    prep_k<<<12645, 256, 0, stream>>>(gw1, gw2, gw3, gw4, cw1, wp1, wp2, wp3, w4p, wp5, zp);

    // L1: MFMA IC=1 conv (grid 10240)
    convmm1_k<128, 32, 3, 4, 1, 4, true, true><<<64 * 40 * 4, 256, 0, stream>>>(
        total, wp1, g1, b1, h1n, 80, 2000, 40, 498, 4, 2);

    // L2: M_BLK=128, waves 2x2 (grid 1280) — R10-verified config
    convmm_k<128, 64, 32, 1, 2, 2, 5><<<64 * 20, 256, 0, stream>>>(
        h1n, wp2, g2, b2, h2n, 40, 498, 20, 122, 1);

    // L3: M_BLK=32, OC=128, waves 1x4 (grid 640) — R10-verified config
    convmm_k<32, 128, 64, 2, 1, 4, 5><<<64 * 10, 256, 0, stream>>>(
        h2n, wp3, g3, b3, h3n, 20, 122, 10, 28, 1);

    // L4: implicit-im2col MFMA GEMM, split-K x4 (grid 400)
    gemm4_k<<<400, 256, 0, stream>>>(h3n, w4p, zp, part);

    // routing head sums partials + BN + GELU + pool + FCs + top-2
    route_k<<<64, 256, 0, stream>>>(part, g4, b4, fw1, fb1, g1d, b1d, fw2, fb2, rw, sel);

    // gather: 512000 groups of 4
    gather_k<<<2000, 256, 0, stream>>>(x, sel, (uint4*)gated);

    // L5: MFMA IC=1 conv via (t,s) factorization (grid 17920)
    convmm1_k<64, 64, 4, 2, 2, 2, false, false><<<64 * 40 * 7, 256, 0, stream>>>(
        gated, wp5, nullptr, nullptr, outc, 80, 400, 40, 397, 7, 3);
}